// Round 1
// baseline (10.392 us; speedup 1.0000x reference)
//
#include <hip/hip_runtime.h>
#include <math.h>

// BehlerG2 angular symmetry function, fused.
// Shapes: r_ij/r_ik/r_jk/mask: (B,N,T) f32; etas: (E,)=16; zetas: (Z,)=4.
// Output: (B,N,E*2Z) = (B*N, 128) f32.
//
// f[e,z]   = c_z  * S[e, z&3],  c_z = 2^(1-zeta) (z<4) or 2^(1+zeta) (z>=4)
// S[e,j]   = sum_t w_t * exp(-r2_t * eta_e) * base_t^{zeta_j}
// w_t      = mask_t * fc(r_ij) fc(r_ik) fc(r_jk)
// base_t   = 1 - cos_theta (cos masked to 0 where mask==0)

#define T_TRIP 512
#define E_N 16

__global__ __launch_bounds__(256) void behler_g2_kernel(
    const float* __restrict__ r_ij, const float* __restrict__ r_ik,
    const float* __restrict__ r_jk, const float* __restrict__ mask,
    const float* __restrict__ etas, const float* __restrict__ zetas,
    float* __restrict__ out)
{
    __shared__ float2 WR[T_TRIP];   // (w, r2) per triple
    __shared__ float4 P[T_TRIP];    // base^{zeta_j}, j=0..3 per triple
    __shared__ float  red[4][E_N][4]; // per-wave partial sums

    const int blk = blockIdx.x;            // flattened (b*N + n)
    const int tid = threadIdx.x;
    const size_t base_in = (size_t)blk * T_TRIP;

    const float z0 = zetas[0], z1 = zetas[1], z2 = zetas[2], z3 = zetas[3];
    const bool fastz = (z0 == 1.0f && z1 == 2.0f && z2 == 4.0f && z3 == 8.0f);

    const float PI_OVER_RC = 0.52359877559829887f;   // pi / 6
    const float LOG2E      = 1.4426950408889634f;

    // ---- Phase 1: per-triple scalar stage (each thread: 2 triples) ----
    for (int t = tid; t < T_TRIP; t += 256) {
        float a = r_ij[base_in + t];
        float b = r_ik[base_in + t];
        float c = r_jk[base_in + t];
        float m = mask[base_in + t];
        float r2 = a * a + b * b + c * c;
        float fa = (a < 6.0f) ? 0.5f * (__cosf(a * PI_OVER_RC) + 1.0f) : 0.0f;
        float fb = (b < 6.0f) ? 0.5f * (__cosf(b * PI_OVER_RC) + 1.0f) : 0.0f;
        float fcv = (c < 6.0f) ? 0.5f * (__cosf(c * PI_OVER_RC) + 1.0f) : 0.0f;
        float w = m * fa * fb * fcv;
        float ct = r2 / (2.0f * a * b);
        if (m == 0.0f) ct = 0.0f;
        float bs = 1.0f - ct;
        float4 p;
        if (fastz) {
            p.x = bs;
            p.y = bs * bs;
            p.z = p.y * p.y;
            p.w = p.z * p.z;
        } else {
            p.x = powf(bs, z0);
            p.y = powf(bs, z1);
            p.z = powf(bs, z2);
            p.w = powf(bs, z3);
        }
        WR[t] = make_float2(w, r2);
        P[t] = p;
    }
    __syncthreads();

    // ---- Phase 2: 16 groups of 16 lanes; lane = eta index e ----
    const int g = tid >> 4;      // group 0..15, handles t == g (mod 16)
    const int e = tid & 15;
    const float me = -etas[e] * LOG2E;   // exp(-r2*eta) = exp2(r2*me)

    float acc0 = 0.0f, acc1 = 0.0f, acc2 = 0.0f, acc3 = 0.0f;
    #pragma unroll
    for (int i = 0; i < T_TRIP / 16; ++i) {
        int t = (i << 4) + g;
        float2 wr = WR[t];
        float4 p = P[t];
        float x = exp2f(wr.y * me) * wr.x;
        acc0 = fmaf(x, p.x, acc0);
        acc1 = fmaf(x, p.y, acc1);
        acc2 = fmaf(x, p.z, acc2);
        acc3 = fmaf(x, p.w, acc3);
    }

    // reduce the 4 groups within each wave (lanes l, l+16, l+32, l+48)
    acc0 += __shfl_down(acc0, 32); acc0 += __shfl_down(acc0, 16);
    acc1 += __shfl_down(acc1, 32); acc1 += __shfl_down(acc1, 16);
    acc2 += __shfl_down(acc2, 32); acc2 += __shfl_down(acc2, 16);
    acc3 += __shfl_down(acc3, 32); acc3 += __shfl_down(acc3, 16);

    const int wave = tid >> 6;
    if ((tid & 63) < 16) {
        red[wave][e][0] = acc0;
        red[wave][e][1] = acc1;
        red[wave][e][2] = acc2;
        red[wave][e][3] = acc3;
    }
    __syncthreads();

    // ---- Epilogue: combine wave partials, apply 2^(1±zeta), write 128 outs ----
    if (tid < 128) {
        int ee = tid >> 3, z = tid & 7, j = z & 3;
        float s = red[0][ee][j] + red[1][ee][j] + red[2][ee][j] + red[3][ee][j];
        float zj = zetas[j];
        float coef = exp2f((z < 4) ? (1.0f - zj) : (1.0f + zj));
        out[(size_t)blk * 128 + tid] = coef * s;
    }
}

extern "C" void kernel_launch(void* const* d_in, const int* in_sizes, int n_in,
                              void* d_out, int out_size, void* d_ws, size_t ws_size,
                              hipStream_t stream) {
    const float* r_ij = (const float*)d_in[0];
    const float* r_ik = (const float*)d_in[1];
    const float* r_jk = (const float*)d_in[2];
    const float* mask = (const float*)d_in[3];
    const float* etas = (const float*)d_in[4];
    const float* zetas = (const float*)d_in[5];
    float* out = (float*)d_out;

    int nblk = out_size / 128;   // B*N rows, 128 outputs each
    behler_g2_kernel<<<nblk, 256, 0, stream>>>(r_ij, r_ik, r_jk, mask,
                                               etas, zetas, out);
}

// Round 2
// 9.734 us; speedup vs baseline: 1.0675x; 1.0675x over previous
//
#include <hip/hip_runtime.h>
#include <math.h>

// BehlerG2 angular symmetry function, fused. Single kernel, one block per
// (b,n) row: phase 1 stages per-triple scalars into LDS (w folded into the
// base-power vector), phase 2 is a 16-lane-group eta scan, then a wave/LDS
// reduction and the 2^(1±zeta) epilogue.
//
// f[e,z]   = c_z  * S[e, z&3],  c_z = 2^(1-zeta) (z<4) or 2^(1+zeta) (z>=4)
// S[e,j]   = sum_t exp(-r2_t * eta_e) * [w_t * base_t^{zeta_j}]
// w_t      = mask_t * fc(r_ij) fc(r_ik) fc(r_jk)

#define T_TRIP 512
#define E_N 16

__global__ __launch_bounds__(256) void behler_g2_kernel(
    const float* __restrict__ r_ij, const float* __restrict__ r_ik,
    const float* __restrict__ r_jk, const float* __restrict__ mask,
    const float* __restrict__ etas, const float* __restrict__ zetas,
    float* __restrict__ out)
{
    __shared__ float  R2[T_TRIP];     // r2 per triple
    __shared__ float4 P[T_TRIP];      // w * base^{zeta_j}, j=0..3
    __shared__ float  red[4][E_N][4]; // per-wave partial sums

    const int blk = blockIdx.x;            // flattened (b*N + n)
    const int tid = threadIdx.x;
    const size_t b2 = (size_t)blk * (T_TRIP / 2) + tid;  // float2 index

    const float z0 = zetas[0], z1 = zetas[1], z2 = zetas[2], z3 = zetas[3];
    const bool fastz = (z0 == 1.0f && z1 == 2.0f && z2 == 4.0f && z3 == 8.0f);
    const float PI_OVER_RC = 0.52359877559829887f;   // pi / 6

    // ---- Phase 1: vectorized loads, per-triple scalar stage ----
    const float2 va = ((const float2*)r_ij)[b2];
    const float2 vb = ((const float2*)r_ik)[b2];
    const float2 vc = ((const float2*)r_jk)[b2];
    const float2 vm = ((const float2*)mask)[b2];

    float r2s[2];
    float4 ps[2];
    #pragma unroll
    for (int k = 0; k < 2; ++k) {
        float a = k ? va.y : va.x;
        float b = k ? vb.y : vb.x;
        float c = k ? vc.y : vc.x;
        float m = k ? vm.y : vm.x;
        float r2 = fmaf(a, a, fmaf(b, b, c * c));
        float fa  = (a < 6.0f) ? 0.5f * (__cosf(a * PI_OVER_RC) + 1.0f) : 0.0f;
        float fb  = (b < 6.0f) ? 0.5f * (__cosf(b * PI_OVER_RC) + 1.0f) : 0.0f;
        float fcv = (c < 6.0f) ? 0.5f * (__cosf(c * PI_OVER_RC) + 1.0f) : 0.0f;
        float w = m * fa * fb * fcv;
        float ct = __fdividef(r2, 2.0f * a * b);
        float4 p;
        if (fastz) {
            float bs = 1.0f - ct;          // w==0 annihilates any magnitude here
            float b2v = bs * bs, b4 = b2v * b2v, b8 = b4 * b4;
            p = make_float4(w * bs, w * b2v, w * b4, w * b8);
        } else {
            if (m == 0.0f) ct = 0.0f;      // avoid NaN from powf(neg, frac)
            float bs = 1.0f - ct;
            p = make_float4(w * powf(bs, z0), w * powf(bs, z1),
                            w * powf(bs, z2), w * powf(bs, z3));
        }
        r2s[k] = r2;
        ps[k] = p;
    }
    ((float2*)R2)[tid] = make_float2(r2s[0], r2s[1]);
    P[2 * tid]     = ps[0];
    P[2 * tid + 1] = ps[1];
    __syncthreads();

    // ---- Phase 2: 16 groups of 16 lanes; lane = eta index e ----
    const int g = tid >> 4;          // group handles t == g (mod 16)
    const int e = tid & 15;
    const float me = -etas[e];

    float acc0 = 0.0f, acc1 = 0.0f, acc2 = 0.0f, acc3 = 0.0f;
    #pragma unroll
    for (int i = 0; i < T_TRIP / 16; ++i) {
        int t = (i << 4) + g;
        float x = __expf(R2[t] * me);   // v_mul + v_exp
        float4 p = P[t];                // broadcast b128, conflict-free
        acc0 = fmaf(x, p.x, acc0);
        acc1 = fmaf(x, p.y, acc1);
        acc2 = fmaf(x, p.z, acc2);
        acc3 = fmaf(x, p.w, acc3);
    }

    // reduce the 4 groups within each wave (lanes l, l+16, l+32, l+48)
    acc0 += __shfl_down(acc0, 32); acc0 += __shfl_down(acc0, 16);
    acc1 += __shfl_down(acc1, 32); acc1 += __shfl_down(acc1, 16);
    acc2 += __shfl_down(acc2, 32); acc2 += __shfl_down(acc2, 16);
    acc3 += __shfl_down(acc3, 32); acc3 += __shfl_down(acc3, 16);

    const int wave = tid >> 6;
    if ((tid & 63) < 16) {
        red[wave][e][0] = acc0;
        red[wave][e][1] = acc1;
        red[wave][e][2] = acc2;
        red[wave][e][3] = acc3;
    }
    __syncthreads();

    // ---- Epilogue: combine wave partials, apply 2^(1±zeta) ----
    if (tid < 128) {
        int ee = tid >> 3, z = tid & 7, j = z & 3;
        float s = red[0][ee][j] + red[1][ee][j] + red[2][ee][j] + red[3][ee][j];
        float zj = zetas[j];
        float coef = exp2f((z < 4) ? (1.0f - zj) : (1.0f + zj));
        out[(size_t)blk * 128 + tid] = coef * s;
    }
}

extern "C" void kernel_launch(void* const* d_in, const int* in_sizes, int n_in,
                              void* d_out, int out_size, void* d_ws, size_t ws_size,
                              hipStream_t stream) {
    const float* r_ij = (const float*)d_in[0];
    const float* r_ik = (const float*)d_in[1];
    const float* r_jk = (const float*)d_in[2];
    const float* mask = (const float*)d_in[3];
    const float* etas = (const float*)d_in[4];
    const float* zetas = (const float*)d_in[5];
    float* out = (float*)d_out;

    int nblk = out_size / 128;   // B*N rows, 128 outputs each
    behler_g2_kernel<<<nblk, 256, 0, stream>>>(r_ij, r_ik, r_jk, mask,
                                               etas, zetas, out);
}